// Round 3
// baseline (8195.165 us; speedup 1.0000x reference)
//
#include <hip/hip_runtime.h>
#include <hip/hip_fp16.h>

#define B_ 64
#define T_ 512
#define I_ 128
#define H_ 512

typedef _Float16 half2v __attribute__((ext_vector_type(2)));

__device__ __forceinline__ float dot2(unsigned a, unsigned b, float c) {
    return __builtin_amdgcn_fdot2(__builtin_bit_cast(half2v, a),
                                  __builtin_bit_cast(half2v, b), c, false);
}

__device__ __forceinline__ unsigned short f32_to_f16b(float f) {
    _Float16 h = (_Float16)f;
    return __builtin_bit_cast(unsigned short, h);
}

// ---------------------------------------------------------------------------
// Kernel 1: W_hid fp32 [H,H] -> packed f16 pairs, k-split layout.
// Consumer: block (b,q), wave w, lane l, slot i in [0,8), group g in [0,4):
//   h = l + 64*i ; k-pair kp = 128*q + 16*w + 4*g + m (m = dword in uint4)
//   uint4 index u = ((q*8+w)*32 + i*4+g)*64 + l
// Also zeroes the 128 exchange flags (stale-flag safety across launches).
// ---------------------------------------------------------------------------
__global__ void wconv(const float* __restrict__ Whid,
                      unsigned* __restrict__ Wz,
                      int* __restrict__ flags) {
    if (blockIdx.x == 0 && threadIdx.x < 128)
        flags[threadIdx.x * 16] = 0;
    int p = blockIdx.x * 256 + threadIdx.x;   // dword index, 0..131071
    int m  = p & 3;
    int u4 = p >> 2;
    int l = u4 & 63;
    int r = u4 >> 6;                  // 0..511
    int g = r & 3;
    int i = (r >> 2) & 7;
    int w = (r >> 5) & 7;
    int q = (r >> 8) & 1;
    int h  = l + 64 * i;
    int kp = 128 * q + 16 * w + 4 * g + m;
    float w0 = Whid[h * H_ + 2 * kp];
    float w1 = Whid[h * H_ + 2 * kp + 1];
    half2v hw = { (_Float16)w0, (_Float16)w1 };
    Wz[p] = __builtin_bit_cast(unsigned, hw);
}

// ---------------------------------------------------------------------------
// Kernel 2: v_in[b,t,h] = x[b,t,:] @ W_in[h,:] + b_in[h]  (unchanged from R2)
// ---------------------------------------------------------------------------
__global__ __launch_bounds__(256) void vin_gemm(const float* __restrict__ x,
                                                const float* __restrict__ Win,
                                                const float* __restrict__ bin,
                                                float* __restrict__ vin) {
    __shared__ __align__(16) unsigned xs[64 * 64];   // 16 KB
    __shared__ __align__(16) unsigned ws[64 * 64];   // 16 KB
    const int tid = threadIdx.x;
    const int m0 = blockIdx.x * 64;
    const int n0 = blockIdx.y * 64;

    #pragma unroll
    for (int r = 0; r < 8; ++r) {
        int gi = r * 256 + tid;       // 0..2047
        int row = gi >> 5;            // 0..63
        int c4 = gi & 31;             // float4 index in the 128-float row
        float4 vx = ((const float4*)(x + (size_t)(m0 + row) * I_))[c4];
        float4 vw = ((const float4*)(Win + (size_t)(n0 + row) * I_))[c4];
        int sw = (row >> 2) & 15;
        int col = 4 * ((c4 >> 1) ^ sw) + (c4 & 1) * 2;  // swizzled dword col
        half2v x01 = { (_Float16)vx.x, (_Float16)vx.y };
        half2v x23 = { (_Float16)vx.z, (_Float16)vx.w };
        half2v w01 = { (_Float16)vw.x, (_Float16)vw.y };
        half2v w23 = { (_Float16)vw.z, (_Float16)vw.w };
        xs[row * 64 + col]     = __builtin_bit_cast(unsigned, x01);
        xs[row * 64 + col + 1] = __builtin_bit_cast(unsigned, x23);
        ws[row * 64 + col]     = __builtin_bit_cast(unsigned, w01);
        ws[row * 64 + col + 1] = __builtin_bit_cast(unsigned, w23);
    }
    __syncthreads();

    const int ty = tid >> 4, tx = tid & 15;
    float acc[4][4] = {};
    #pragma unroll
    for (int kb = 0; kb < 16; ++kb) {
        uint4 a4[4], b4[4];
        #pragma unroll
        for (int i = 0; i < 4; ++i)
            a4[i] = *(const uint4*)&xs[(ty * 4 + i) * 64 + 4 * (kb ^ ty)];
        #pragma unroll
        for (int j = 0; j < 4; ++j)
            b4[j] = *(const uint4*)&ws[(tx * 4 + j) * 64 + 4 * (kb ^ tx)];
        #pragma unroll
        for (int i = 0; i < 4; ++i)
            #pragma unroll
            for (int j = 0; j < 4; ++j) {
                acc[i][j] = dot2(a4[i].x, b4[j].x, acc[i][j]);
                acc[i][j] = dot2(a4[i].y, b4[j].y, acc[i][j]);
                acc[i][j] = dot2(a4[i].z, b4[j].z, acc[i][j]);
                acc[i][j] = dot2(a4[i].w, b4[j].w, acc[i][j]);
            }
    }

    float4 bv = ((const float4*)(bin + n0))[tx];
    #pragma unroll
    for (int i = 0; i < 4; ++i) {
        int m = m0 + ty * 4 + i;
        float4 o;
        o.x = acc[i][0] + bv.x; o.y = acc[i][1] + bv.y;
        o.z = acc[i][2] + bv.z; o.w = acc[i][3] + bv.w;
        ((float4*)(vin + (size_t)m * H_ + n0))[tx] = o;
    }
}

// ---------------------------------------------------------------------------
// Kernel 3: recurrence, TWO blocks per batch (k-split).  Block bq:
//   b = bq & 63, q = bq >> 6  (pairing (i, i+64) -> same XCD under %8 RR).
// Block (b,q) owns k in [256q, 256q+256); wave w owns k in [256q+32w, +32).
// W = 128 dwords/thread, fully VGPR-resident (no ldsW, no spill).
// Both blocks compute the full v-update for all 512 h (fr is local);
// only the 512 k-partial sums are exchanged per step via L2 (agent-scope
// atomics, release/acquire flag, parity double-buffer).
// Block 0 stores out0, block 1 stores out1.
// ---------------------------------------------------------------------------
__global__ __launch_bounds__(512, 2)
__attribute__((amdgpu_waves_per_eu(2, 2)))
void recurrent(
        const uint4* __restrict__ Wz4,
        const float* __restrict__ vin,
        const float* __restrict__ init_state,
        const float* __restrict__ b_hid,
        const float* __restrict__ alpha,
        float* __restrict__ out0,
        float* __restrict__ out1,
        float* __restrict__ pxbuf,
        int* __restrict__ flags) {
    __shared__ uint4 frbuf4[2][64];     //  2 KB : fr as f16 pairs, dbuf
    __shared__ float pbuf[8][576];      // 18 KB : partials [w][l*9+i], stride 9

    const int t = threadIdx.x;
    const int bq = blockIdx.x;          // 0..127
    const int b = bq & 63;
    const int q = bq >> 6;
    const int w = t >> 6, l = t & 63;

    // ---- all W into VGPRs: 32 coalesced uint4 loads (128 dwords) ---------
    uint4 wv[8][4];
    const uint4* wp = Wz4 + (size_t)((q * 8 + w) * 32) * 64 + l;
    #pragma unroll
    for (int i = 0; i < 8; ++i)
        #pragma unroll
        for (int g = 0; g < 4; ++g)
            wv[i][g] = wp[(i * 4 + g) * 64];
    #pragma unroll
    for (int i = 0; i < 8; ++i)
        #pragma unroll
        for (int g = 0; g < 4; ++g)
            asm volatile("" : "+v"(wv[i][g].x), "+v"(wv[i][g].y),
                              "+v"(wv[i][g].z), "+v"(wv[i][g].w));

    // ---- init ------------------------------------------------------------
    unsigned short* fr16 = (unsigned short*)frbuf4;   // [2][512]
    float v = init_state[b * H_ + t];
    fr16[t] = f32_to_f16b(fmaxf(v, 0.0f));
    const float bh = b_hid[t];
    const float al = alpha[t];
    const float om = 1.0f - al;

    const float* vinp = vin + (size_t)b * T_ * H_ + t;
    float* op = (q == 0 ? out0 : out1) + (size_t)b * T_ * H_ + t;

    // exchange pointers: pxbuf[b][par][q][512]
    float* px_out0 = pxbuf + (size_t)((b * 2 + 0) * 2 + q) * 512 + t;
    float* px_out1 = pxbuf + (size_t)((b * 2 + 1) * 2 + q) * 512 + t;
    const float* px_in0 = pxbuf + (size_t)((b * 2 + 0) * 2 + (1 - q)) * 512 + t;
    const float* px_in1 = pxbuf + (size_t)((b * 2 + 1) * 2 + (1 - q)) * 512 + t;
    int* myflag = flags + (b * 2 + q) * 16;
    int* pflag  = flags + (b * 2 + (1 - q)) * 16;

    __syncthreads();

    for (int s = 0; s < T_; ++s) {
        const int par = s & 1;
        float vinv = vinp[(size_t)s * H_];        // early issue, used late

        const uint4* fb = &frbuf4[par][32 * q + 4 * w];  // wave-uniform
        float a[8] = {};

        #pragma unroll
        for (int g = 0; g < 4; ++g) {
            uint4 f = fb[g];                      // broadcast b128
            #pragma unroll
            for (int i = 0; i < 8; ++i) {
                a[i] = dot2(f.x, wv[i][g].x, a[i]);
                a[i] = dot2(f.y, wv[i][g].y, a[i]);
                a[i] = dot2(f.z, wv[i][g].z, a[i]);
                a[i] = dot2(f.w, wv[i][g].w, a[i]);
            }
        }

        // partial writes: 8 x b32, odd stride 9 -> 2 lanes/bank (free)
        #pragma unroll
        for (int i = 0; i < 8; ++i) pbuf[w][l * 9 + i] = a[i];

        asm volatile("s_waitcnt lgkmcnt(0)" ::: "memory");
        __builtin_amdgcn_s_barrier();             // A: partials visible

        // local k-half reduce: thread t owns h = t (reads bank-conflict-free)
        float sum = pbuf[0][l * 9 + w] + pbuf[1][l * 9 + w]
                  + pbuf[2][l * 9 + w] + pbuf[3][l * 9 + w]
                  + pbuf[4][l * 9 + w] + pbuf[5][l * 9 + w]
                  + pbuf[6][l * 9 + w] + pbuf[7][l * 9 + w];

        // publish k-half partial (agent-coherent store)
        __hip_atomic_store(par ? px_out1 : px_out0, sum,
                           __ATOMIC_RELAXED, __HIP_MEMORY_SCOPE_AGENT);
        asm volatile("s_waitcnt vmcnt(0)" ::: "memory");
        __builtin_amdgcn_s_barrier();             // B: all lanes published

        if (t == 0)
            __hip_atomic_store(myflag, s + 1,
                               __ATOMIC_RELEASE, __HIP_MEMORY_SCOPE_AGENT);

        // wait for partner's k-half of this step
        while (__hip_atomic_load(pflag, __ATOMIC_ACQUIRE,
                                 __HIP_MEMORY_SCOPE_AGENT) < s + 1) { }
        float pp = __hip_atomic_load(par ? px_in1 : px_in0,
                                     __ATOMIC_RELAXED, __HIP_MEMORY_SCOPE_AGENT);

        float vhid = sum + pp + bh;
        float vnew = om * v + al * (vhid + vinv);
        float vr   = om * vnew + al * vhid;
        v = vnew;
        float frn = fmaxf(vnew, 0.0f);
        float frr = fmaxf(vr, 0.0f);

        fr16[(par ^ 1) * 512 + t] = f32_to_f16b(frn);
        op[(size_t)s * H_] = (q == 0 ? frn : frr);   // fire-and-forget

        asm volatile("s_waitcnt lgkmcnt(0)" ::: "memory");
        __builtin_amdgcn_s_barrier();             // C: fr visible, pbuf free
    }
}

// ---------------------------------------------------------------------------
extern "C" void kernel_launch(void* const* d_in, const int* in_sizes, int n_in,
                              void* d_out, int out_size, void* d_ws, size_t ws_size,
                              hipStream_t stream) {
    const float* x          = (const float*)d_in[0];
    const float* init_state = (const float*)d_in[1];
    const float* W_in       = (const float*)d_in[2];
    const float* b_in       = (const float*)d_in[3];
    const float* W_hid      = (const float*)d_in[4];
    const float* b_hid      = (const float*)d_in[5];
    const float* alpha      = (const float*)d_in[6];

    float* out0 = (float*)d_out;
    float* out1 = out0 + (size_t)B_ * T_ * H_;

    char* ws = (char*)d_ws;
    float*    vin   = (float*)ws;                       // 67,108,864 B
    unsigned* Wz    = (unsigned*)(ws + 67108864);       //    524,288 B
    float*    pxbuf = (float*)(ws + 67108864 + 524288); //    524,288 B
    int*      flags = (int*)(ws + 67108864 + 1048576);  //      8,192 B

    hipLaunchKernelGGL(wconv, dim3(512), dim3(256), 0, stream,
                       W_hid, Wz, flags);
    hipLaunchKernelGGL(vin_gemm, dim3(512, 8), dim3(256), 0, stream,
                       x, W_in, b_in, vin);
    hipLaunchKernelGGL(recurrent, dim3(128), dim3(512), 0, stream,
                       (const uint4*)Wz, vin, init_state, b_hid, alpha,
                       out0, out1, pxbuf, flags);
}